// Round 3
// baseline (709.190 us; speedup 1.0000x reference)
//
#include <hip/hip_runtime.h>

// Problem constants
#define BQ      8
#define SEQ     4096
#define DIM_    1024
#define QKVD    3072
#define NPATCH  206     // patch rows; token t = 40*(r>>1) + 2*s + (r&1), s in [0,20)
#define MTOT    (BQ * SEQ)

typedef __bf16 bf16x8 __attribute__((ext_vector_type(8)));
typedef float  f32x4  __attribute__((ext_vector_type(4)));

__device__ __forceinline__ float bf2f(unsigned int u16) {
  union { unsigned int i; float f; } x;
  x.i = u16 << 16;
  return x.f;
}
__device__ __forceinline__ unsigned short f2bf(float f) {
  union { float f; unsigned int i; } x; x.f = f;
  unsigned int r = x.i + 0x7fffu + ((x.i >> 16) & 1u);  // RNE
  return (unsigned short)(r >> 16);
}

__device__ __forceinline__ void load_lds16(const void* g, void* l) {
  __builtin_amdgcn_global_load_lds(
      (const __attribute__((address_space(1))) void*)g,
      (__attribute__((address_space(3))) void*)l, 16, 0, 0);
}

// fp32 -> bf16 (RNE) conversion for x, Wqkv, Wout in one pass.
__global__ __launch_bounds__(256) void cvt_kernel(
    const float* __restrict__ x,  unsigned short* __restrict__ xb,
    const float* __restrict__ w1, unsigned short* __restrict__ w1b,
    const float* __restrict__ w2, unsigned short* __restrict__ w2b)
{
  const long long NX  = (long long)MTOT * DIM_;
  const long long NW1 = (long long)QKVD * DIM_;
  const long long NW2 = (long long)DIM_ * DIM_;
  const long long total4 = (NX + NW1 + NW2) >> 2;
  for (long long q = (long long)blockIdx.x * 256 + threadIdx.x; q < total4;
       q += (long long)gridDim.x * 256) {
    const float* src; unsigned short* dst; long long i;
    if (q < (NX >> 2))              { src = x;  dst = xb;  i = (q << 2); }
    else if (q < ((NX + NW1) >> 2)) { src = w1; dst = w1b; i = (q << 2) - NX; }
    else                            { src = w2; dst = w2b; i = (q << 2) - NX - NW1; }
    float4 v = *(const float4*)(src + i);
    ushort4 o;
    o.x = f2bf(v.x); o.y = f2bf(v.y); o.z = f2bf(v.z); o.w = f2bf(v.w);
    *(ushort4*)(dst + i) = o;
  }
}

// ---------------------------------------------------------------------------
// 256x256 tile GEMM (R1-exact schedule, best measured 224us for gemm1).
// C[M,N] = A[M,K] * B[N,K]^T, bf16 in, fp32 accum, bf16 out.
// 512 threads = 8 waves (2M x 4N), BK=64, double-buffered LDS (128 KiB),
// 4-phase-per-K-tile, counted vmcnt(4).
// ---------------------------------------------------------------------------
#define MFMA_Q(IH, JH)                                                        \
  _Pragma("unroll") for (int i_ = 0; i_ < 4; ++i_)                            \
  _Pragma("unroll") for (int j_ = 0; j_ < 2; ++j_) {                          \
    acc[(IH)*4 + i_][(JH)*2 + j_] = __builtin_amdgcn_mfma_f32_16x16x32_bf16(  \
        af[IH][i_][0], bf_[j_][0], acc[(IH)*4 + i_][(JH)*2 + j_], 0, 0, 0);   \
    acc[(IH)*4 + i_][(JH)*2 + j_] = __builtin_amdgcn_mfma_f32_16x16x32_bf16(  \
        af[IH][i_][1], bf_[j_][1], acc[(IH)*4 + i_][(JH)*2 + j_], 0, 0, 0);   \
  }

#define STAGE_A(H, KT, BUF) do {                                              \
    const int kof_ = (KT) * 64;                                               \
    unsigned short* d_ = &lds[(BUF) * 32768 + (H) * 8192 + tid * 8];          \
    load_lds16(a_src0 + (size_t)(H) * 128 * K + kof_, d_);                    \
    load_lds16(a_src1 + (size_t)(H) * 128 * K + kof_, d_ + 4096);             \
  } while (0)

#define STAGE_B(H, KT, BUF) do {                                              \
    const int kof_ = (KT) * 64;                                               \
    unsigned short* d_ = &lds[(BUF) * 32768 + 16384 + (H) * 8192 + tid * 8];  \
    load_lds16(b_src0 + (size_t)(H) * 128 * K + kof_, d_);                    \
    load_lds16(b_src1 + (size_t)(H) * 128 * K + kof_, d_ + 4096);             \
  } while (0)

#define OPEN_BARRIER  __builtin_amdgcn_s_barrier()
#define CLOSE_BARRIER asm volatile("s_barrier" ::: "memory")
#define WAIT_LGKM0    asm volatile("s_waitcnt lgkmcnt(0)" ::: "memory")

__global__ __launch_bounds__(512, 2) void gemm_bt256(
    const unsigned short* __restrict__ A,
    const unsigned short* __restrict__ Bm,
    void* __restrict__ Cv,
    int N, int K)
{
  __shared__ alignas(16) unsigned short lds[2 * 32768];  // 128 KiB

  const int tid  = threadIdx.x;
  const int wave = tid >> 6;
  const int lane = tid & 63;
  const int wr = wave >> 2;        // 0..1 : wave row  (owns 128 M-rows)
  const int wc = wave & 3;         // 0..3 : wave col  (owns 64 N-cols)
  const int fr = lane & 15;        // fragment row
  const int fq = lane >> 4;        // k-chunk 0..3
  const size_t bm = (size_t)blockIdx.y * 256;
  const size_t bn = (size_t)blockIdx.x * 256;

  // --- staging source (row, col) inside a 128x64 half-tile, 2 passes ---
  int r_s[2], c_s[2];
#pragma unroll
  for (int p = 0; p < 2; ++p) {
    int byte = (p * 512 + tid) * 16;
    int lo = byte ^ (((byte >> 7) & 7) << 4);
    r_s[p] = lo >> 7;
    c_s[p] = (lo & 127) >> 1;
  }
  const unsigned short* a_src0 = A  + (bm + r_s[0]) * (size_t)K + c_s[0];
  const unsigned short* a_src1 = A  + (bm + r_s[1]) * (size_t)K + c_s[1];
  const unsigned short* b_src0 = Bm + (bn + r_s[0]) * (size_t)K + c_s[0];
  const unsigned short* b_src1 = Bm + (bn + r_s[1]) * (size_t)K + c_s[1];

  // --- fragment-read offsets (ushort units, swizzled; row bits fold out) ---
  const int offu0 = ((fr * 128 +  0 + fq * 16) ^ ((fr & 7) << 4)) >> 1;  // kk=0
  const int offu1 = ((fr * 128 + 64 + fq * 16) ^ ((fr & 7) << 4)) >> 1;  // kk=1
  const int awo = wr * 8192;                                  // A half base
  const int bwo = 16384 + (wc >> 1) * 8192 + (wc & 1) * 4096; // B panel base

  f32x4 acc[8][4];
#pragma unroll
  for (int i = 0; i < 8; ++i)
#pragma unroll
    for (int j = 0; j < 4; ++j)
      acc[i][j] = (f32x4){0.f, 0.f, 0.f, 0.f};

  const int NT = K >> 6;  // K-tiles of 64

  // --- prologue: tile0 full (buf0) + A halves of tile1 (buf1) ---
  STAGE_B(0, 0, 0); STAGE_B(1, 0, 0);
  STAGE_A(0, 0, 0); STAGE_A(1, 0, 0);
  STAGE_A(0, 1, 1); STAGE_A(1, 1, 1);
  asm volatile("s_waitcnt vmcnt(4)" ::: "memory");   // tile0 fully landed
  __builtin_amdgcn_s_barrier();

  bf16x8 af[2][4][2];   // [ihalf][i][kk]
  bf16x8 bf_[2][2];     // [j-pair slot][kk] (reused jLo -> jHi)

  for (int T = 0; T < NT; ++T) {
    const int cur = T & 1;
    const unsigned short* bufc = &lds[cur * 32768];
    const int ktB = (T + 1 < NT) ? T + 1 : NT - 1;
    const int ktA = (T + 2 < NT) ? T + 2 : NT - 1;

    // ---- phase 1: read A-lo + B-jLo, stage B0(T+1)->nxt, MFMA (iLo,jLo)
#pragma unroll
    for (int i = 0; i < 4; ++i) {
      af[0][i][0] = *(const bf16x8*)&bufc[awo + i * 1024 + offu0];
      af[0][i][1] = *(const bf16x8*)&bufc[awo + i * 1024 + offu1];
    }
#pragma unroll
    for (int j = 0; j < 2; ++j) {
      bf_[j][0] = *(const bf16x8*)&bufc[bwo + j * 1024 + offu0];
      bf_[j][1] = *(const bf16x8*)&bufc[bwo + j * 1024 + offu1];
    }
    STAGE_B(0, ktB, cur ^ 1);
    OPEN_BARRIER;
    WAIT_LGKM0;
    __builtin_amdgcn_s_setprio(1);
    MFMA_Q(0, 0)
    __builtin_amdgcn_s_setprio(0);
    CLOSE_BARRIER;

    // ---- phase 2: read A-hi, stage B1(T+1)->nxt, MFMA (iHi,jLo)
#pragma unroll
    for (int i = 0; i < 4; ++i) {
      af[1][i][0] = *(const bf16x8*)&bufc[awo + 4096 + i * 1024 + offu0];
      af[1][i][1] = *(const bf16x8*)&bufc[awo + 4096 + i * 1024 + offu1];
    }
    STAGE_B(1, ktB, cur ^ 1);
    OPEN_BARRIER;
    WAIT_LGKM0;
    __builtin_amdgcn_s_setprio(1);
    MFMA_Q(1, 0)
    __builtin_amdgcn_s_setprio(0);
    CLOSE_BARRIER;

    // ---- phase 3: read B-jHi, stage A0(T+2)->cur, MFMA (iLo,jHi)
#pragma unroll
    for (int j = 0; j < 2; ++j) {
      bf_[j][0] = *(const bf16x8*)&bufc[bwo + 2048 + j * 1024 + offu0];
      bf_[j][1] = *(const bf16x8*)&bufc[bwo + 2048 + j * 1024 + offu1];
    }
    STAGE_A(0, ktA, cur);
    OPEN_BARRIER;
    WAIT_LGKM0;
    __builtin_amdgcn_s_setprio(1);
    MFMA_Q(0, 1)
    __builtin_amdgcn_s_setprio(0);
    CLOSE_BARRIER;

    // ---- phase 4: stage A1(T+2)->cur, MFMA (iHi,jHi), counted vmcnt
    STAGE_A(1, ktA, cur);
    OPEN_BARRIER;
    __builtin_amdgcn_s_setprio(1);
    MFMA_Q(1, 1)
    __builtin_amdgcn_s_setprio(0);
    asm volatile("s_waitcnt vmcnt(4)" ::: "memory");  // tile T+1 fully landed
    CLOSE_BARRIER;
  }

  // Epilogue: C/D layout col = lane&15, row = (lane>>4)*4 + reg  [m89/m91]
  const int crow0 = fq * 4;
  const int ccol  = fr;
#pragma unroll
  for (int i = 0; i < 8; ++i) {
#pragma unroll
    for (int j = 0; j < 4; ++j) {
      size_t base = (bm + wr * 128 + i * 16 + crow0) * (size_t)N
                  + (bn + wc * 64 + j * 16 + ccol);
#pragma unroll
      for (int r2 = 0; r2 < 4; ++r2) {
        ((unsigned short*)Cv)[base + (size_t)r2 * N] = f2bf(acc[i][j][r2]);
      }
    }
  }
}

// ---------------------------------------------------------------------------
// 128x128 tile GEMM (R0 kernel) — used for gemm2 (N=1024, 2048 blocks,
// 16 KiB LDS -> multiple blocks/CU for TLP).  256 threads = 4 waves, BK=32.
// ---------------------------------------------------------------------------
template <bool HAS_BIAS, bool OUT_F32>
__global__ __launch_bounds__(256) void gemm_bt128(
    const unsigned short* __restrict__ A,
    const unsigned short* __restrict__ Bm,
    const float* __restrict__ bias,
    void* __restrict__ Cv,
    int N, int K)
{
  __shared__ alignas(16) unsigned short As[128 * 32];
  __shared__ alignas(16) unsigned short Bs[128 * 32];

  const int tid  = threadIdx.x;
  const size_t bm = (size_t)blockIdx.y * 128;
  const size_t bn = (size_t)blockIdx.x * 128;
  const int wave = tid >> 6;
  const int lane = tid & 63;
  const int wm = (wave >> 1) * 64;
  const int wn = (wave & 1) * 64;
  const int fr = lane & 15;       // fragment row (m for A, n for B)
  const int fq = lane >> 4;       // k-chunk index 0..3 (k offset = fq*8)

  f32x4 acc[4][4];
#pragma unroll
  for (int i = 0; i < 4; ++i)
#pragma unroll
    for (int j = 0; j < 4; ++j)
      acc[i][j] = (f32x4){0.f, 0.f, 0.f, 0.f};

  // staging with XOR-swizzled source chunk
  const int srow  = tid >> 2;
  const int c_src = (tid & 3) ^ ((tid >> 3) & 3);
  const int scol  = c_src * 8;
  const unsigned short* gA0 = A  + (bm + srow) * (size_t)K + scol;
  const unsigned short* gA1 = A  + (bm + 64 + srow) * (size_t)K + scol;
  const unsigned short* gB0 = Bm + (bn + srow) * (size_t)K + scol;
  const unsigned short* gB1 = Bm + (bn + 64 + srow) * (size_t)K + scol;
  unsigned short* lA0 = &As[tid * 8];
  unsigned short* lA1 = &As[2048 + tid * 8];
  unsigned short* lB0 = &Bs[tid * 8];
  unsigned short* lB1 = &Bs[2048 + tid * 8];

  // fragment-read offset within each 512-elem (16-row) group
  const int frx = fr * 32 + ((fq ^ ((fr >> 1) & 3)) * 8);
  const int ga0 = ((wm >> 4) + 0) * 512 + frx;
  const int gb0 = ((wn >> 4) + 0) * 512 + frx;

  for (int kt = 0; kt < K; kt += 32) {
    load_lds16(gA0 + kt, lA0);
    load_lds16(gA1 + kt, lA1);
    load_lds16(gB0 + kt, lB0);
    load_lds16(gB1 + kt, lB1);
    __syncthreads();

    bf16x8 af[4], bfm[4];
#pragma unroll
    for (int i = 0; i < 4; ++i)
      af[i] = *(const bf16x8*)(&As[ga0 + i * 512]);
#pragma unroll
    for (int j = 0; j < 4; ++j)
      bfm[j] = *(const bf16x8*)(&Bs[gb0 + j * 512]);
#pragma unroll
    for (int i = 0; i < 4; ++i)
#pragma unroll
      for (int j = 0; j < 4; ++j)
        acc[i][j] = __builtin_amdgcn_mfma_f32_16x16x32_bf16(af[i], bfm[j], acc[i][j], 0, 0, 0);
    __syncthreads();
  }

  // Epilogue: C/D layout col = lane&15, row = (lane>>4)*4 + reg  [m89/m91]
  const int crow0 = (lane >> 4) * 4;
  const int ccol  = lane & 15;
  float bv[4];
  if (HAS_BIAS) {
#pragma unroll
    for (int j = 0; j < 4; ++j) bv[j] = bias[bn + wn + j * 16 + ccol];
  }
#pragma unroll
  for (int i = 0; i < 4; ++i) {
#pragma unroll
    for (int j = 0; j < 4; ++j) {
      size_t base = (bm + wm + i * 16 + crow0) * (size_t)N + (bn + wn + j * 16 + ccol);
#pragma unroll
      for (int r2 = 0; r2 < 4; ++r2) {
        float v = acc[i][j][r2];
        if (HAS_BIAS) v += bv[j];
        if (OUT_F32) ((float*)Cv)[base + (size_t)r2 * N] = v;
        else ((unsigned short*)Cv)[base + (size_t)r2 * N] = f2bf(v);
      }
    }
  }
}

// Per-patch attention. Block = (patch r, head-half, batch), 256 threads.
// K staged as fp32 in LDS (decoded once), V as bf16; logits read K via
// ds_read_b128, PV vectorized over 4-elem chunks. Pad tokens -> K=V=0,
// logits 0 participate in softmax (matches reference); pad queries skipped.
#define KSF 516   // float stride per token (512 + 4)
#define VST 520   // ushort stride per token (512 + 8)
__global__ __launch_bounds__(256) void attn_kernel(
    const unsigned short* __restrict__ qkv,
    unsigned short* __restrict__ y)
{
  const int r    = blockIdx.x;   // 0..205
  const int half = blockIdx.y;   // 0..1
  const int b    = blockIdx.z;   // 0..7
  const int tid  = threadIdx.x;
  const int tbase = 40 * (r >> 1) + (r & 1);
  const int hq_off = half * 512;

  __shared__ alignas(16) float Ksf[20 * KSF];            // 41280 B
  __shared__ alignas(16) unsigned short Vs[20 * VST];    // 20800 B
  __shared__ float L[8 * 20 * 20];                       // 12800 B

  // ---- stage: 20 tokens x (K 512 + V 512), 8-elem items ----
  for (int c = tid; c < 2560; c += 256) {
    int tok = c >> 7;
    int kv  = (c >> 6) & 1;
    int j   = c & 63;
    int t   = tbase + 2 * tok;
    int4 data;
    if (t < SEQ) {
      const unsigned short* src = qkv + ((size_t)(b * SEQ + t)) * QKVD
                                  + 1024 + kv * 1024 + hq_off + j * 8;
      data = *(const int4*)src;
    } else {
      data = make_int4(0, 0, 0, 0);
    }
    if (kv == 0) {
      const unsigned short* u = (const unsigned short*)&data;
      float4 f0, f1;
      f0.x = bf2f(u[0]); f0.y = bf2f(u[1]); f0.z = bf2f(u[2]); f0.w = bf2f(u[3]);
      f1.x = bf2f(u[4]); f1.y = bf2f(u[5]); f1.z = bf2f(u[6]); f1.w = bf2f(u[7]);
      *(float4*)(&Ksf[tok * KSF + j * 8])     = f0;
      *(float4*)(&Ksf[tok * KSF + j * 8 + 4]) = f1;
    } else {
      *(int4*)(&Vs[tok * VST + j * 8]) = data;
    }
  }
  __syncthreads();

  // ---- logits: 8h x 20s x 20u dots of length 64 ----
  for (int i = tid; i < 3200; i += 256) {
    int h   = i / 400;
    int rem = i - h * 400;
    int s   = rem / 20;
    int u   = rem - s * 20;
    int tq  = tbase + 2 * s;
    float dot = 0.f;
    if (tq < SEQ) {
      const int2* q64 = (const int2*)(qkv + (size_t)(b * SEQ + tq) * QKVD + hq_off + h * 64);
      const f32x4* kf = (const f32x4*)(&Ksf[u * KSF + h * 64]);
#pragma unroll
      for (int e4 = 0; e4 < 16; ++e4) {
        int2 qa = q64[e4];
        f32x4 kv4 = kf[e4];
        dot += bf2f((unsigned int)qa.x & 0xffffu) * kv4.x
             + bf2f((unsigned int)qa.x >> 16)     * kv4.y
             + bf2f((unsigned int)qa.y & 0xffffu) * kv4.z
             + bf2f((unsigned int)qa.y >> 16)     * kv4.w;
      }
    }
    L[(h * 20 + s) * 20 + u] = dot * 0.125f;
  }
  __syncthreads();

  // ---- softmax over 20 keys, one thread per (h, s) ----
  if (tid < 160) {
    int h = tid / 20;
    int s = tid - h * 20;
    float* row = &L[(h * 20 + s) * 20];
    float m = -1e30f;
#pragma unroll
    for (int u = 0; u < 20; ++u) m = fmaxf(m, row[u]);
    float w[20];
    float sum = 0.f;
#pragma unroll
    for (int u = 0; u < 20; ++u) { w[u] = __expf(row[u] - m); sum += w[u]; }
    float inv = 1.f / sum;
#pragma unroll
    for (int u = 0; u < 20; ++u) row[u] = w[u] * inv;
  }
  __syncthreads();

  // ---- PV: 8h x 20s x 16 e4-chunks; ushort4 stores ----
  for (int i = tid; i < 2560; i += 256) {
    int e4   = i & 15;
    int rest = i >> 4;
    int s    = rest % 20;
    int h    = rest / 20;
    int tq   = tbase + 2 * s;
    if (tq >= SEQ) continue;
    const float* w = &L[(h * 20 + s) * 20];
    const unsigned short* vp = Vs + h * 64 + e4 * 4;
    float a0 = 0.f, a1 = 0.f, a2 = 0.f, a3 = 0.f;
#pragma unroll
    for (int u = 0; u < 20; ++u) {
      float wu = w[u];
      uint2 vv = *(const uint2*)(vp + u * VST);
      a0 += wu * bf2f(vv.x & 0xffffu);
      a1 += wu * bf2f(vv.x >> 16);
      a2 += wu * bf2f(vv.y & 0xffffu);
      a3 += wu * bf2f(vv.y >> 16);
    }
    ushort4 o;
    o.x = f2bf(a0); o.y = f2bf(a1); o.z = f2bf(a2); o.w = f2bf(a3);
    *(ushort4*)(&y[(size_t)(b * SEQ + tq) * DIM_ + hq_off + h * 64 + e4 * 4]) = o;
  }
}

extern "C" void kernel_launch(void* const* d_in, const int* in_sizes, int n_in,
                              void* d_out, int out_size, void* d_ws, size_t ws_size,
                              hipStream_t stream) {
  const float* x    = (const float*)d_in[0];  // [8,4096,1024] fp32
  const float* Wqkv = (const float*)d_in[1];  // [3072,1024]  fp32
  const float* Wout = (const float*)d_in[2];  // [1024,1024]  fp32
  const float* bout = (const float*)d_in[3];  // [1024]       fp32
  float* out = (float*)d_out;                 // [8,4096,1024] fp32

  unsigned short* xb_y  = (unsigned short*)d_ws;           // x bf16, reused as y
  unsigned short* wqkvb = xb_y  + (size_t)MTOT * DIM_;
  unsigned short* woutb = wqkvb + (size_t)QKVD * DIM_;
  unsigned short* qkv   = woutb + (size_t)DIM_ * DIM_;

  // 0) fp32 -> bf16
  cvt_kernel<<<2048, 256, 0, stream>>>(x, xb_y, Wqkv, wqkvb, Wout, woutb);

  // 1) qkv = x @ Wqkv^T   (M=32768, N=3072, K=1024), bf16 out — 256^2 kernel
  gemm_bt256<<<dim3(QKVD / 256, MTOT / 256), 512, 0, stream>>>(
      xb_y, wqkvb, qkv, QKVD, DIM_);

  // 2) per-patch attention (y overwrites xb)
  attn_kernel<<<dim3(NPATCH, 2, BQ), 256, 0, stream>>>(qkv, xb_y);

  // 3) out = y @ Wout^T + bout   (M=32768, N=1024, K=1024), fp32 out — 128^2
  gemm_bt128<true, true><<<dim3(DIM_ / 128, MTOT / 128), 256, 0, stream>>>(
      xb_y, woutb, bout, out, DIM_, DIM_);
}

// Round 5
// 576.826 us; speedup vs baseline: 1.2295x; 1.2295x over previous
//
#include <hip/hip_runtime.h>

// Problem constants
#define BQ      8
#define SEQ     4096
#define DIM_    1024
#define QKVD    3072
#define NPATCH  206     // patch rows; token t = 40*(r>>1) + 2*s + (r&1), s in [0,20)
#define MTOT    (BQ * SEQ)

typedef __bf16 bf16x8 __attribute__((ext_vector_type(8)));
typedef float  f32x4  __attribute__((ext_vector_type(4)));

__device__ __forceinline__ float bf2f(unsigned int u16) {
  union { unsigned int i; float f; } x;
  x.i = u16 << 16;
  return x.f;
}
__device__ __forceinline__ unsigned short f2bf(float f) {
  union { float f; unsigned int i; } x; x.f = f;
  unsigned int r = x.i + 0x7fffu + ((x.i >> 16) & 1u);  // RNE
  return (unsigned short)(r >> 16);
}

__device__ __forceinline__ void load_lds16(const void* g, void* l) {
  __builtin_amdgcn_global_load_lds(
      (const __attribute__((address_space(1))) void*)g,
      (__attribute__((address_space(3))) void*)l, 16, 0, 0);
}

// fp32 -> bf16 (RNE) conversion for x, Wqkv, Wout in one pass.
__global__ __launch_bounds__(256) void cvt_kernel(
    const float* __restrict__ x,  unsigned short* __restrict__ xb,
    const float* __restrict__ w1, unsigned short* __restrict__ w1b,
    const float* __restrict__ w2, unsigned short* __restrict__ w2b)
{
  const long long NX  = (long long)MTOT * DIM_;
  const long long NW1 = (long long)QKVD * DIM_;
  const long long NW2 = (long long)DIM_ * DIM_;
  const long long total4 = (NX + NW1 + NW2) >> 2;
  for (long long q = (long long)blockIdx.x * 256 + threadIdx.x; q < total4;
       q += (long long)gridDim.x * 256) {
    const float* src; unsigned short* dst; long long i;
    if (q < (NX >> 2))              { src = x;  dst = xb;  i = (q << 2); }
    else if (q < ((NX + NW1) >> 2)) { src = w1; dst = w1b; i = (q << 2) - NX; }
    else                            { src = w2; dst = w2b; i = (q << 2) - NX - NW1; }
    float4 v = *(const float4*)(src + i);
    ushort4 o;
    o.x = f2bf(v.x); o.y = f2bf(v.y); o.z = f2bf(v.z); o.w = f2bf(v.w);
    *(ushort4*)(dst + i) = o;
  }
}

// ---------------------------------------------------------------------------
// 256x256 tile GEMM (R1 schedule, best measured 216us for gemm1).
// C[M,N] = A[M,K] * B[N,K]^T (+bias), bf16 in, fp32 accum, bf16/fp32 out.
// 512 threads = 8 waves (2M x 4N), BK=64, double-buffered LDS (128 KiB),
// 4-phase-per-K-tile, counted vmcnt(4).
// ---------------------------------------------------------------------------
#define MFMA_Q(IH, JH)                                                        \
  _Pragma("unroll") for (int i_ = 0; i_ < 4; ++i_)                            \
  _Pragma("unroll") for (int j_ = 0; j_ < 2; ++j_) {                          \
    acc[(IH)*4 + i_][(JH)*2 + j_] = __builtin_amdgcn_mfma_f32_16x16x32_bf16(  \
        af[IH][i_][0], bf_[j_][0], acc[(IH)*4 + i_][(JH)*2 + j_], 0, 0, 0);   \
    acc[(IH)*4 + i_][(JH)*2 + j_] = __builtin_amdgcn_mfma_f32_16x16x32_bf16(  \
        af[IH][i_][1], bf_[j_][1], acc[(IH)*4 + i_][(JH)*2 + j_], 0, 0, 0);   \
  }

#define STAGE_A(H, KT, BUF) do {                                              \
    const int kof_ = (KT) * 64;                                               \
    unsigned short* d_ = &lds[(BUF) * 32768 + (H) * 8192 + tid * 8];          \
    load_lds16(a_src0 + (size_t)(H) * 128 * K + kof_, d_);                    \
    load_lds16(a_src1 + (size_t)(H) * 128 * K + kof_, d_ + 4096);             \
  } while (0)

#define STAGE_B(H, KT, BUF) do {                                              \
    const int kof_ = (KT) * 64;                                               \
    unsigned short* d_ = &lds[(BUF) * 32768 + 16384 + (H) * 8192 + tid * 8];  \
    load_lds16(b_src0 + (size_t)(H) * 128 * K + kof_, d_);                    \
    load_lds16(b_src1 + (size_t)(H) * 128 * K + kof_, d_ + 4096);             \
  } while (0)

#define OPEN_BARRIER  __builtin_amdgcn_s_barrier()
#define CLOSE_BARRIER asm volatile("s_barrier" ::: "memory")
#define WAIT_LGKM0    asm volatile("s_waitcnt lgkmcnt(0)" ::: "memory")

template <bool HAS_BIAS, bool OUT_F32>
__global__ __launch_bounds__(512, 2) void gemm_bt256(
    const unsigned short* __restrict__ A,
    const unsigned short* __restrict__ Bm,
    const float* __restrict__ bias,
    void* __restrict__ Cv,
    int N, int K)
{
  __shared__ alignas(16) unsigned short lds[2 * 32768];  // 128 KiB

  const int tid  = threadIdx.x;
  const int wave = tid >> 6;
  const int lane = tid & 63;
  const int wr = wave >> 2;        // 0..1 : wave row  (owns 128 M-rows)
  const int wc = wave & 3;         // 0..3 : wave col  (owns 64 N-cols)
  const int fr = lane & 15;        // fragment row
  const int fq = lane >> 4;        // k-chunk 0..3
  const size_t bm = (size_t)blockIdx.y * 256;
  const size_t bn = (size_t)blockIdx.x * 256;

  // --- staging source (row, col) inside a 128x64 half-tile, 2 passes ---
  int r_s[2], c_s[2];
#pragma unroll
  for (int p = 0; p < 2; ++p) {
    int byte = (p * 512 + tid) * 16;
    int lo = byte ^ (((byte >> 7) & 7) << 4);
    r_s[p] = lo >> 7;
    c_s[p] = (lo & 127) >> 1;
  }
  const unsigned short* a_src0 = A  + (bm + r_s[0]) * (size_t)K + c_s[0];
  const unsigned short* a_src1 = A  + (bm + r_s[1]) * (size_t)K + c_s[1];
  const unsigned short* b_src0 = Bm + (bn + r_s[0]) * (size_t)K + c_s[0];
  const unsigned short* b_src1 = Bm + (bn + r_s[1]) * (size_t)K + c_s[1];

  // --- fragment-read offsets (ushort units, swizzled; row bits fold out) ---
  const int offu0 = ((fr * 128 +  0 + fq * 16) ^ ((fr & 7) << 4)) >> 1;  // kk=0
  const int offu1 = ((fr * 128 + 64 + fq * 16) ^ ((fr & 7) << 4)) >> 1;  // kk=1
  const int awo = wr * 8192;                                  // A half base
  const int bwo = 16384 + (wc >> 1) * 8192 + (wc & 1) * 4096; // B panel base

  f32x4 acc[8][4];
#pragma unroll
  for (int i = 0; i < 8; ++i)
#pragma unroll
    for (int j = 0; j < 4; ++j)
      acc[i][j] = (f32x4){0.f, 0.f, 0.f, 0.f};

  const int NT = K >> 6;  // K-tiles of 64

  // --- prologue: tile0 full (buf0) + A halves of tile1 (buf1) ---
  STAGE_B(0, 0, 0); STAGE_B(1, 0, 0);
  STAGE_A(0, 0, 0); STAGE_A(1, 0, 0);
  STAGE_A(0, 1, 1); STAGE_A(1, 1, 1);
  asm volatile("s_waitcnt vmcnt(4)" ::: "memory");   // tile0 fully landed
  __builtin_amdgcn_s_barrier();

  bf16x8 af[2][4][2];   // [ihalf][i][kk]
  bf16x8 bf_[2][2];     // [j-pair slot][kk] (reused jLo -> jHi)

  for (int T = 0; T < NT; ++T) {
    const int cur = T & 1;
    const unsigned short* bufc = &lds[cur * 32768];
    const int ktB = (T + 1 < NT) ? T + 1 : NT - 1;
    const int ktA = (T + 2 < NT) ? T + 2 : NT - 1;

    // ---- phase 1: read A-lo + B-jLo, stage B0(T+1)->nxt, MFMA (iLo,jLo)
#pragma unroll
    for (int i = 0; i < 4; ++i) {
      af[0][i][0] = *(const bf16x8*)&bufc[awo + i * 1024 + offu0];
      af[0][i][1] = *(const bf16x8*)&bufc[awo + i * 1024 + offu1];
    }
#pragma unroll
    for (int j = 0; j < 2; ++j) {
      bf_[j][0] = *(const bf16x8*)&bufc[bwo + j * 1024 + offu0];
      bf_[j][1] = *(const bf16x8*)&bufc[bwo + j * 1024 + offu1];
    }
    STAGE_B(0, ktB, cur ^ 1);
    OPEN_BARRIER;
    WAIT_LGKM0;
    __builtin_amdgcn_s_setprio(1);
    MFMA_Q(0, 0)
    __builtin_amdgcn_s_setprio(0);
    CLOSE_BARRIER;

    // ---- phase 2: read A-hi, stage B1(T+1)->nxt, MFMA (iHi,jLo)
#pragma unroll
    for (int i = 0; i < 4; ++i) {
      af[1][i][0] = *(const bf16x8*)&bufc[awo + 4096 + i * 1024 + offu0];
      af[1][i][1] = *(const bf16x8*)&bufc[awo + 4096 + i * 1024 + offu1];
    }
    STAGE_B(1, ktB, cur ^ 1);
    OPEN_BARRIER;
    WAIT_LGKM0;
    __builtin_amdgcn_s_setprio(1);
    MFMA_Q(1, 0)
    __builtin_amdgcn_s_setprio(0);
    CLOSE_BARRIER;

    // ---- phase 3: read B-jHi, stage A0(T+2)->cur, MFMA (iLo,jHi)
#pragma unroll
    for (int j = 0; j < 2; ++j) {
      bf_[j][0] = *(const bf16x8*)&bufc[bwo + 2048 + j * 1024 + offu0];
      bf_[j][1] = *(const bf16x8*)&bufc[bwo + 2048 + j * 1024 + offu1];
    }
    STAGE_A(0, ktA, cur);
    OPEN_BARRIER;
    WAIT_LGKM0;
    __builtin_amdgcn_s_setprio(1);
    MFMA_Q(0, 1)
    __builtin_amdgcn_s_setprio(0);
    CLOSE_BARRIER;

    // ---- phase 4: stage A1(T+2)->cur, MFMA (iHi,jHi), counted vmcnt
    STAGE_A(1, ktA, cur);
    OPEN_BARRIER;
    __builtin_amdgcn_s_setprio(1);
    MFMA_Q(1, 1)
    __builtin_amdgcn_s_setprio(0);
    asm volatile("s_waitcnt vmcnt(4)" ::: "memory");  // tile T+1 fully landed
    CLOSE_BARRIER;
  }

  // Epilogue: C/D layout col = lane&15, row = (lane>>4)*4 + reg  [m89/m91]
  const int crow0 = fq * 4;
  const int ccol  = fr;
  float bv[4];
  if (HAS_BIAS) {
#pragma unroll
    for (int j = 0; j < 4; ++j) bv[j] = bias[bn + wc * 64 + j * 16 + ccol];
  }
#pragma unroll
  for (int i = 0; i < 8; ++i) {
#pragma unroll
    for (int j = 0; j < 4; ++j) {
      size_t base = (bm + wr * 128 + i * 16 + crow0) * (size_t)N
                  + (bn + wc * 64 + j * 16 + ccol);
#pragma unroll
      for (int r2 = 0; r2 < 4; ++r2) {
        float v = acc[i][j][r2];
        if (HAS_BIAS) v += bv[j];
        if (OUT_F32) ((float*)Cv)[base + (size_t)r2 * N] = v;
        else ((unsigned short*)Cv)[base + (size_t)r2 * N] = f2bf(v);
      }
    }
  }
}

// ---------------------------------------------------------------------------
// MFMA attention. Block = (patch r, head-half, batch), 256 thr = 4 waves.
// Each wave independently handles 2 heads: ZERO barriers (all LDS sharing is
// intra-wave; same-wave DS ops complete in order + compiler lgkmcnt).
//   QK^T: Q/K fragments read directly from global (clamped tokens), 8 MFMA
//         16x16x32 per head; C/D layout: row s = fq*4+r2 (+m*16), col u = fr.
//   softmax: quarter-wave shfl_xor reduce; pad-key logits forced to 0
//         (reference zero-pads K); P stored UNNORMALIZED (<=1) as bf16 in
//         fragment-direct LDS layout [lane][8]; 1/sum applied at epilogue.
//   PV: V staged coalesced to LDS [u][66] (stride chosen conflict-free for
//         the 8xu16 transpose gather), 8 MFMA per head; s<20 store guard.
// ---------------------------------------------------------------------------
#define VHS 2120              // ushort stride per head's V region ([32][66]+pad)
#define PWS 2048              // ushort size of per-wave P region
#define WSZ (2*VHS + PWS)     // 6288 ushorts per wave
__global__ __launch_bounds__(256, 3) void attn_kernel(
    const unsigned short* __restrict__ qkv,
    unsigned short* __restrict__ y)
{
  __shared__ alignas(16) unsigned short SM[4 * WSZ];   // 50304 B

  const int r    = blockIdx.x;   // 0..205
  const int half = blockIdx.y;   // 0..1
  const int b    = blockIdx.z;   // 0..7
  const int tid  = threadIdx.x;
  const int wave = tid >> 6;
  const int lane = tid & 63;
  const int fq   = lane >> 4;    // quarter  (k-chunk / C-row group)
  const int fr   = lane & 15;    // fragment row / C-col
  const int tbase = 40 * (r >> 1) + (r & 1);
  const int hq   = half * 512;   // ushort offset of this half within a token
  const size_t rowB = (size_t)b * SEQ;

  unsigned short* W  = &SM[wave * WSZ];
  unsigned short* Ps = W + 2 * VHS;

  // number of valid (non-pad) key indices u: tbase + 2u < SEQ
  const int ulim = (SEQ - tbase + 1) >> 1;

  // ---- zero per-wave V + P regions (covers pad keys / pad P slots) ----
  const int4 z4 = make_int4(0, 0, 0, 0);
  for (int z = lane; z < (2 * VHS) / 8; z += 64) *(int4*)(W + z * 8) = z4;
  for (int z = lane; z < PWS / 8; z += 64)       *(int4*)(Ps + z * 8) = z4;

  // ---- stage V for this wave's 2 heads: [u<20][66]-strided rows ----
  for (int c = lane; c < 320; c += 64) {
    int u  = c >> 4;
    int hl = (c >> 3) & 1;
    int d8 = c & 7;
    int t  = tbase + 2 * u;
    if (t < SEQ) {
      const unsigned short* src = qkv + (rowB + t) * (size_t)QKVD
                                  + 2048 + hq + (wave * 2 + hl) * 64 + d8 * 8;
      int4 v = *(const int4*)src;
      unsigned short* dst = W + hl * VHS + u * 66 + d8 * 8;
      *(unsigned int*)(dst)     = (unsigned int)v.x;
      *(unsigned int*)(dst + 2) = (unsigned int)v.y;
      *(unsigned int*)(dst + 4) = (unsigned int)v.z;
      *(unsigned int*)(dst + 6) = (unsigned int)v.w;
    }
  }

  // ---- per-lane Q/K token rows (clamped; pad rows masked later) ----
  int tok0 = tbase + 2 * fr;          if (tok0 > SEQ - 1) tok0 = SEQ - 1;
  int tok1 = tbase + 2 * (16 + fr);   if (tok1 > SEQ - 1) tok1 = SEQ - 1;
  const unsigned short* row0 = qkv + (rowB + tok0) * (size_t)QKVD;
  const unsigned short* row1 = qkv + (rowB + tok1) * (size_t)QKVD;

#pragma unroll
  for (int hl = 0; hl < 2; ++hl) {
    const int ho = hq + (wave * 2 + hl) * 64;

    // ---- Q/K fragments direct from global ----
    bf16x8 aQ[2][2], bK[2][2];   // [tile][kk]
#pragma unroll
    for (int kk = 0; kk < 2; ++kk) {
      aQ[0][kk] = *(const bf16x8*)(row0 + ho + kk * 32 + fq * 8);
      aQ[1][kk] = *(const bf16x8*)(row1 + ho + kk * 32 + fq * 8);
      bK[0][kk] = *(const bf16x8*)(row0 + 1024 + ho + kk * 32 + fq * 8);
      bK[1][kk] = *(const bf16x8*)(row1 + 1024 + ho + kk * 32 + fq * 8);
    }

    // ---- QK^T: acc[m][n][r2] = dot(q_{s}, k_{u}),  s=m*16+fq*4+r2, u=n*16+fr
    f32x4 acc[2][2];
#pragma unroll
    for (int m = 0; m < 2; ++m)
#pragma unroll
      for (int n = 0; n < 2; ++n)
        acc[m][n] = (f32x4){0.f, 0.f, 0.f, 0.f};
#pragma unroll
    for (int kk = 0; kk < 2; ++kk)
#pragma unroll
      for (int m = 0; m < 2; ++m)
#pragma unroll
        for (int n = 0; n < 2; ++n)
          acc[m][n] = __builtin_amdgcn_mfma_f32_16x16x32_bf16(
              aQ[m][kk], bK[n][kk], acc[m][n], 0, 0, 0);

    // ---- softmax over u (20 keys), quarter-wave parallel ----
    float ex0[2][4], ex1[2][4], inv_[2][4];
    const bool u1v = (fr < 4);
#pragma unroll
    for (int m = 0; m < 2; ++m) {
#pragma unroll
      for (int q2 = 0; q2 < 4; ++q2) {
        float v0 = acc[m][0][q2] * 0.125f;
        float v1 = acc[m][1][q2] * 0.125f;
        if (fr >= ulim) v0 = 0.f;          // pad key -> logit 0 (matches ref)
        if (16 + fr >= ulim) v1 = 0.f;
        float mx = u1v ? fmaxf(v0, v1) : v0;
        mx = fmaxf(mx, __shfl_xor(mx, 1));
        mx = fmaxf(mx, __shfl_xor(mx, 2));
        mx = fmaxf(mx, __shfl_xor(mx, 4));
        mx = fmaxf(mx, __shfl_xor(mx, 8));
        float e0 = __expf(v0 - mx);
        float e1 = u1v ? __expf(v1 - mx) : 0.f;
        float sm = e0 + e1;
        sm += __shfl_xor(sm, 1);
        sm += __shfl_xor(sm, 2);
        sm += __shfl_xor(sm, 4);
        sm += __shfl_xor(sm, 8);
        ex0[m][q2] = e0; ex1[m][q2] = e1;
        inv_[m][q2] = 1.f / sm;
      }
    }

    // ---- write P (bf16, unnormalized) into fragment-direct layout ----
    // P(s,u) -> Ps[(u>>3)*16 + (s&15)][u&7]
#pragma unroll
    for (int m = 0; m < 2; ++m) {
      unsigned short* pb = Ps + (hl * 2 + m) * 512;
#pragma unroll
      for (int q2 = 0; q2 < 4; ++q2) {
        pb[((fr >> 3) * 16 + fq * 4 + q2) * 8 + (fr & 7)] = f2bf(ex0[m][q2]);
        if (u1v) pb[(32 + fq * 4 + q2) * 8 + fr] = f2bf(ex1[m][q2]);
      }
    }

    // ---- PV: out[s][d] = sum_u P[s][u] V[u][d] ----
    bf16x8 pA[2];
#pragma unroll
    for (int m = 0; m < 2; ++m)
      pA[m] = *(const bf16x8*)(Ps + (hl * 2 + m) * 512 + lane * 8);

    f32x4 o[2][4];
#pragma unroll
    for (int n = 0; n < 4; ++n) {
      union { unsigned short s[8]; bf16x8 v; } g;
#pragma unroll
      for (int j = 0; j < 8; ++j)
        g.s[j] = W[hl * VHS + (fq * 8 + j) * 66 + n * 16 + fr];
#pragma unroll
      for (int m = 0; m < 2; ++m)
        o[m][n] = __builtin_amdgcn_mfma_f32_16x16x32_bf16(
            pA[m], g.v, (f32x4){0.f, 0.f, 0.f, 0.f}, 0, 0, 0);
    }

    // ---- epilogue: scale by 1/sum, store valid query rows ----
#pragma unroll
    for (int m = 0; m < 2; ++m) {
#pragma unroll
      for (int q2 = 0; q2 < 4; ++q2) {
        int s = m * 16 + fq * 4 + q2;
        int t = tbase + 2 * s;
        if (s < 20 && t < SEQ) {
          size_t yb = (rowB + t) * (size_t)DIM_ + ho;
#pragma unroll
          for (int n = 0; n < 4; ++n)
            y[yb + n * 16 + fr] = f2bf(o[m][n][q2] * inv_[m][q2]);
        }
      }
    }
  }
}

extern "C" void kernel_launch(void* const* d_in, const int* in_sizes, int n_in,
                              void* d_out, int out_size, void* d_ws, size_t ws_size,
                              hipStream_t stream) {
  const float* x    = (const float*)d_in[0];  // [8,4096,1024] fp32
  const float* Wqkv = (const float*)d_in[1];  // [3072,1024]  fp32
  const float* Wout = (const float*)d_in[2];  // [1024,1024]  fp32
  const float* bout = (const float*)d_in[3];  // [1024]       fp32
  float* out = (float*)d_out;                 // [8,4096,1024] fp32

  unsigned short* xb_y  = (unsigned short*)d_ws;           // x bf16, reused as y
  unsigned short* wqkvb = xb_y  + (size_t)MTOT * DIM_;
  unsigned short* woutb = wqkvb + (size_t)QKVD * DIM_;
  unsigned short* qkv   = woutb + (size_t)DIM_ * DIM_;

  // 0) fp32 -> bf16
  cvt_kernel<<<2048, 256, 0, stream>>>(x, xb_y, Wqkv, wqkvb, Wout, woutb);

  // 1) qkv = x @ Wqkv^T   (M=32768, N=3072, K=1024), bf16 out
  gemm_bt256<false, false><<<dim3(QKVD / 256, MTOT / 256), 512, 0, stream>>>(
      xb_y, wqkvb, nullptr, qkv, QKVD, DIM_);

  // 2) per-patch attention (y overwrites xb)
  attn_kernel<<<dim3(NPATCH, 2, BQ), 256, 0, stream>>>(qkv, xb_y);

  // 3) out = y @ Wout^T + bout   (M=32768, N=1024, K=1024), fp32 out
  gemm_bt256<true, true><<<dim3(DIM_ / 256, MTOT / 256), 512, 0, stream>>>(
      xb_y, woutb, bout, out, DIM_, DIM_);
}